// Round 6
// baseline (782.173 us; speedup 1.0000x reference)
//
#include <hip/hip_runtime.h>
#include <hip/hip_bf16.h>
#include <cstdint>
#include <cstddef>

#define T_TOK 4096
#define DMODEL 1024
#define HIDDEN 2048
#define NEXP 8      // routed experts; z==8 = shared
#define RTOT 8192   // total routed slots = T_TOK * topk (exact)

typedef __bf16 bf16_t;
typedef bf16_t bf16x8 __attribute__((ext_vector_type(8)));
typedef float f32x16 __attribute__((ext_vector_type(16)));

__device__ __forceinline__ void gl_lds16(const void* g, void* l) {
    __builtin_amdgcn_global_load_lds(
        (const __attribute__((address_space(1))) unsigned int*)g,
        (__attribute__((address_space(3))) unsigned int*)l, 16, 0, 0);
}

// ---------------- fused router + x->bf16: one wave per token ----------------
__global__ __launch_bounds__(256) void router_kernel(const float* __restrict__ x,
                                                     const float* __restrict__ wr,
                                                     int* __restrict__ cnt,
                                                     int* __restrict__ tok,    // [8][T_TOK]
                                                     float* __restrict__ gate, // [8][T_TOK]
                                                     int4* __restrict__ pair,
                                                     bf16_t* __restrict__ xb) {
    int token = (blockIdx.x * 256 + threadIdx.x) >> 6;
    int lane = threadIdx.x & 63;
    if (token >= T_TOK) return;
    const float* xr = x + (size_t)token * DMODEL + lane * 16;
    float v[16];
#pragma unroll
    for (int j = 0; j < 4; j++) {
        float4 f = *(const float4*)(xr + j * 4);
        v[j * 4 + 0] = f.x; v[j * 4 + 1] = f.y; v[j * 4 + 2] = f.z; v[j * 4 + 3] = f.w;
    }
    // write bf16 row (lane covers 16 contiguous elems)
    bf16x8 o0, o1;
#pragma unroll
    for (int j = 0; j < 8; j++) { o0[j] = (bf16_t)v[j]; o1[j] = (bf16_t)v[8 + j]; }
    bf16_t* xo = xb + (size_t)token * DMODEL + lane * 16;
    *(bf16x8*)xo = o0;
    *(bf16x8*)(xo + 8) = o1;
    // logits
    float acc[8];
#pragma unroll
    for (int e = 0; e < 8; e++) acc[e] = 0.f;
#pragma unroll
    for (int j = 0; j < 16; j++) {
        const float* w = wr + (size_t)(lane * 16 + j) * 8;
        float xv = v[j];
#pragma unroll
        for (int e = 0; e < 8; e++) acc[e] += xv * w[e];
    }
#pragma unroll
    for (int e = 0; e < 8; e++) {
#pragma unroll
        for (int off = 32; off > 0; off >>= 1) acc[e] += __shfl_down(acc[e], off);
    }
    if (lane == 0) {
        int i1 = 0; float v1 = acc[0];
#pragma unroll
        for (int e = 1; e < 8; e++) if (acc[e] > v1) { v1 = acc[e]; i1 = e; }
        int i2 = -1; float v2 = -1e30f;
#pragma unroll
        for (int e = 0; e < 8; e++) if (e != i1 && acc[e] > v2) { v2 = acc[e]; i2 = e; }
        float g1 = 1.f / (1.f + __expf(v2 - v1));
        float g2 = 1.f - g1;
        int p1 = atomicAdd(&cnt[i1], 1);
        tok[i1 * T_TOK + p1] = token; gate[i1 * T_TOK + p1] = g1;
        int p2 = atomicAdd(&cnt[i2], 1);
        tok[i2 * T_TOK + p2] = token; gate[i2 * T_TOK + p2] = g2;
        pair[token] = make_int4(i1, p1, i2, p2);
    }
}

// ---------------- gather: xg[off(z)+s] = xb[tok[z][s]] (bf16 copy) ----------------
__global__ __launch_bounds__(256) void gather_kernel(const bf16_t* __restrict__ xb,
                                                     const int* __restrict__ cnt,
                                                     const int* __restrict__ tok,
                                                     bf16_t* __restrict__ xg) {
    int sg = blockIdx.x * 2 + (threadIdx.x >> 7);
    int z = sg >> 12, s = sg & 4095;
    if (s >= cnt[z]) return;
    int offz = 0;
    for (int e = 0; e < z; e++) offz += cnt[e];
    int t = tok[z * T_TOK + s];
    int c = threadIdx.x & 127;
    *(bf16x8*)(xg + ((size_t)offz + s) * DMODEL + c * 8) =
        *(const bf16x8*)(xb + (size_t)t * DMODEL + c * 8);
}

// ---------------- transpose+cvt: f32 [R][C] -> bf16 [C][R] ----------------
__global__ __launch_bounds__(256) void transpose_cvt_kernel(const float* __restrict__ w,
                                                            const float* __restrict__ sw,
                                                            bf16_t* __restrict__ out,
                                                            int R, int C) {
    __shared__ float tile[64][65];
    int z = blockIdx.z;
    const float* src = (z < NEXP) ? (w + (size_t)z * R * C) : sw;
    bf16_t* dst = out + (size_t)z * R * C;
    int c0 = blockIdx.x * 64, r0 = blockIdx.y * 64;
    int t = threadIdx.x;
    int lr = t >> 4, lc4 = (t & 15) * 4;
#pragma unroll
    for (int it = 0; it < 4; it++) {
        int r = lr + it * 16;
        float4 v = *(const float4*)&src[(size_t)(r0 + r) * C + c0 + lc4];
        tile[r][lc4 + 0] = v.x; tile[r][lc4 + 1] = v.y;
        tile[r][lc4 + 2] = v.z; tile[r][lc4 + 3] = v.w;
    }
    __syncthreads();
    int wave = t >> 6, lane = t & 63;
#pragma unroll
    for (int it = 0; it < 2; it++) {
        int col = wave * 8 + (lane >> 3) + it * 32;
        int rb = (lane & 7) * 8;
        bf16x8 o;
#pragma unroll
        for (int j = 0; j < 8; j++) o[j] = (bf16_t)tile[rb + j][col];
        *(bf16x8*)&dst[(size_t)(c0 + col) * R + r0 + rb] = o;
    }
}

// ---------------- GEMM1: act = silu(xg@w1)*(xg@w3); 128m x 64n, dbuf 1-barrier ----------------
__global__ __launch_bounds__(256) void gemm1_kernel(
    const bf16_t* __restrict__ xg, const bf16_t* __restrict__ xb,
    const bf16_t* __restrict__ B1base, const bf16_t* __restrict__ B3base,
    const int* __restrict__ cnt, bf16_t* __restrict__ act) {
    const int K = DMODEL, N = HIDDEN;
    const int z = blockIdx.z;
    const int n0 = blockIdx.x * 64, m0 = blockIdx.y * 128;
    int nrow; const bf16_t* Abase; bf16_t* actz;
    if (z < NEXP) {
        int offz = 0;
        for (int e = 0; e < z; e++) offz += cnt[e];
        nrow = cnt[z];
        if (m0 >= nrow) return;
        Abase = xg + (size_t)offz * K;
        actz = act + (size_t)offz * N;
    } else {
        nrow = T_TOK; Abase = xb; actz = act + (size_t)RTOT * N;
    }
    const bf16_t* B1 = B1base + (size_t)z * DMODEL * HIDDEN;
    const bf16_t* B3 = B3base + (size_t)z * DMODEL * HIDDEN;

    __shared__ bf16_t sA[2][4096];   // [buf][4 kc][128 m][8]
    __shared__ bf16_t sB1[2][2048];  // [buf][4 kc][64 n][8]
    __shared__ bf16_t sB3[2][2048];
    const int tid = threadIdx.x, lane = tid & 63, wave = tid >> 6;
    const int hi = lane >> 5, l31 = lane & 31;
    const int wm = (wave >> 1) * 64, wn = (wave & 1) * 32;

    const bf16_t* ga[2]; int loA[2];
#pragma unroll
    for (int i = 0; i < 2; i++) {
        int q = i * 256 + tid;
        int c = q >> 7, mm = q & 127;
        ga[i] = Abase + (size_t)(m0 + mm) * K + c * 8;
        loA[i] = ((i * 2 + (wave >> 1)) * 128 + (wave & 1) * 64) * 8;
    }
    const bf16_t* gb1 = B1 + (size_t)(n0 + lane) * K + wave * 8;
    const bf16_t* gb3 = B3 + (size_t)(n0 + lane) * K + wave * 8;
    const int loB = wave * 64 * 8;

    f32x16 acc1[2], acc3[2];
#pragma unroll
    for (int i = 0; i < 2; i++) { acc1[i] = (f32x16)0.f; acc3[i] = (f32x16)0.f; }

    // prologue: stage k0=0 into buf 0
    gl_lds16(ga[0], &sA[0][loA[0]]);
    gl_lds16(ga[1], &sA[0][loA[1]]);
    gl_lds16(gb1, &sB1[0][loB]);
    gl_lds16(gb3, &sB3[0][loB]);

    int cur = 0;
    for (int k0 = 0; k0 < K; k0 += 32, cur ^= 1) {
        __syncthreads();  // drains in-flight loads -> buf[cur] ready
        if (k0 + 32 < K) {
            int nx = cur ^ 1;
            gl_lds16(ga[0] + k0 + 32, &sA[nx][loA[0]]);
            gl_lds16(ga[1] + k0 + 32, &sA[nx][loA[1]]);
            gl_lds16(gb1 + k0 + 32, &sB1[nx][loB]);
            gl_lds16(gb3 + k0 + 32, &sB3[nx][loB]);
        }
#pragma unroll
        for (int s = 0; s < 2; s++) {
            int kc = s * 2 + hi;
            bf16x8 a0 = *(const bf16x8*)&sA[cur][(kc * 128 + wm + l31) * 8];
            bf16x8 a1 = *(const bf16x8*)&sA[cur][(kc * 128 + wm + 32 + l31) * 8];
            bf16x8 b1f = *(const bf16x8*)&sB1[cur][(kc * 64 + wn + l31) * 8];
            bf16x8 b3f = *(const bf16x8*)&sB3[cur][(kc * 64 + wn + l31) * 8];
            acc1[0] = __builtin_amdgcn_mfma_f32_32x32x16_bf16(a0, b1f, acc1[0], 0, 0, 0);
            acc1[1] = __builtin_amdgcn_mfma_f32_32x32x16_bf16(a1, b1f, acc1[1], 0, 0, 0);
            acc3[0] = __builtin_amdgcn_mfma_f32_32x32x16_bf16(a0, b3f, acc3[0], 0, 0, 0);
            acc3[1] = __builtin_amdgcn_mfma_f32_32x32x16_bf16(a1, b3f, acc3[1], 0, 0, 0);
        }
    }
    // C/D: col=lane&31, row=(reg&3)+8*(reg>>2)+4*(lane>>5)
#pragma unroll
    for (int mt = 0; mt < 2; mt++)
#pragma unroll
        for (int reg = 0; reg < 16; reg++) {
            int m = m0 + wm + mt * 32 + (reg & 3) + 8 * (reg >> 2) + 4 * hi;
            if (m < nrow) {
                int n = n0 + wn + l31;
                float h1 = acc1[mt][reg], h3 = acc3[mt][reg];
                float si = h1 / (1.f + __expf(-h1));
                actz[(size_t)m * N + n] = (bf16_t)(si * h3);
            }
        }
}

// ---------------- GEMM2: 128m x 128n, dbuf 1-barrier; z<8 -> yr gated bf16; z==8 -> d_out ----------------
__global__ __launch_bounds__(256) void gemm2_kernel(const bf16_t* __restrict__ act,
                                                    const bf16_t* __restrict__ Bbase,
                                                    const int* __restrict__ cnt,
                                                    const float* __restrict__ gate,
                                                    bf16_t* __restrict__ yr,
                                                    float* __restrict__ outp) {
    const int K = HIDDEN, N = DMODEL;
    const int z = blockIdx.z;
    const int n0 = blockIdx.x * 128, m0 = blockIdx.y * 128;
    int nrow, o;
    if (z < NEXP) {
        int offz = 0;
        for (int e = 0; e < z; e++) offz += cnt[e];
        nrow = cnt[z];
        if (m0 >= nrow) return;
        o = offz;
    } else {
        nrow = T_TOK; o = RTOT;
    }
    const bf16_t* A = act + (size_t)o * K;
    const bf16_t* B = Bbase + (size_t)z * DMODEL * HIDDEN;

    __shared__ bf16_t sA[2][4096], sB[2][4096];
    const int tid = threadIdx.x, lane = tid & 63, wave = tid >> 6;
    const int hi = lane >> 5, l31 = lane & 31;
    const int wm = (wave >> 1) * 64, wn = (wave & 1) * 64;

    const bf16_t* ga[2]; const bf16_t* gb[2]; int lo[2];
#pragma unroll
    for (int i = 0; i < 2; i++) {
        int q = i * 256 + tid;
        int c = q >> 7, mm = q & 127;
        ga[i] = A + (size_t)(m0 + mm) * K + c * 8;
        gb[i] = B + (size_t)(n0 + mm) * K + c * 8;
        lo[i] = ((i * 2 + (wave >> 1)) * 128 + (wave & 1) * 64) * 8;
    }
    f32x16 acc[2][2];
#pragma unroll
    for (int i = 0; i < 2; i++)
#pragma unroll
        for (int j = 0; j < 2; j++) acc[i][j] = (f32x16)0.f;

    gl_lds16(ga[0], &sA[0][lo[0]]);
    gl_lds16(ga[1], &sA[0][lo[1]]);
    gl_lds16(gb[0], &sB[0][lo[0]]);
    gl_lds16(gb[1], &sB[0][lo[1]]);

    int cur = 0;
    for (int k0 = 0; k0 < K; k0 += 32, cur ^= 1) {
        __syncthreads();
        if (k0 + 32 < K) {
            int nx = cur ^ 1;
            gl_lds16(ga[0] + k0 + 32, &sA[nx][lo[0]]);
            gl_lds16(ga[1] + k0 + 32, &sA[nx][lo[1]]);
            gl_lds16(gb[0] + k0 + 32, &sB[nx][lo[0]]);
            gl_lds16(gb[1] + k0 + 32, &sB[nx][lo[1]]);
        }
#pragma unroll
        for (int s = 0; s < 2; s++) {
            int kc = s * 2 + hi;
            bf16x8 a0 = *(const bf16x8*)&sA[cur][(kc * 128 + wm + l31) * 8];
            bf16x8 a1 = *(const bf16x8*)&sA[cur][(kc * 128 + wm + 32 + l31) * 8];
            bf16x8 b0 = *(const bf16x8*)&sB[cur][(kc * 128 + wn + l31) * 8];
            bf16x8 b1 = *(const bf16x8*)&sB[cur][(kc * 128 + wn + 32 + l31) * 8];
            acc[0][0] = __builtin_amdgcn_mfma_f32_32x32x16_bf16(a0, b0, acc[0][0], 0, 0, 0);
            acc[0][1] = __builtin_amdgcn_mfma_f32_32x32x16_bf16(a0, b1, acc[0][1], 0, 0, 0);
            acc[1][0] = __builtin_amdgcn_mfma_f32_32x32x16_bf16(a1, b0, acc[1][0], 0, 0, 0);
            acc[1][1] = __builtin_amdgcn_mfma_f32_32x32x16_bf16(a1, b1, acc[1][1], 0, 0, 0);
        }
    }
#pragma unroll
    for (int mt = 0; mt < 2; mt++)
#pragma unroll
        for (int reg = 0; reg < 16; reg++) {
            int m = m0 + wm + mt * 32 + (reg & 3) + 8 * (reg >> 2) + 4 * hi;
            if (z == NEXP) {
#pragma unroll
                for (int nt = 0; nt < 2; nt++) {
                    int n = n0 + wn + nt * 32 + l31;
                    outp[(size_t)m * N + n] = acc[mt][nt][reg];
                }
            } else if (m < nrow) {
                float g = gate[z * T_TOK + m];
#pragma unroll
                for (int nt = 0; nt < 2; nt++) {
                    int n = n0 + wn + nt * 32 + l31;
                    yr[((size_t)o + m) * N + n] = (bf16_t)(g * acc[mt][nt][reg]);
                }
            }
        }
}

// ---------------- combine: out[t] += yr[off(e1)+p1] + yr[off(e2)+p2] ----------------
__global__ __launch_bounds__(256) void combine_kernel(const int4* __restrict__ pair,
                                                      const int* __restrict__ cnt,
                                                      const bf16_t* __restrict__ yr,
                                                      float* __restrict__ outp) {
    __shared__ int soff[8];
    if (threadIdx.x < 8) {
        int o = 0;
        for (int e = 0; e < (int)threadIdx.x; e++) o += cnt[e];
        soff[threadIdx.x] = o;
    }
    __syncthreads();
    int t = blockIdx.x;
    int d = threadIdx.x * 4;
    int4 p = pair[t];
    size_t i1 = (size_t)(soff[p.x] + p.y) * DMODEL + d;
    size_t i2 = (size_t)(soff[p.z] + p.w) * DMODEL + d;
    float* op = outp + (size_t)t * DMODEL + d;
    float4 o = *(float4*)op;
    o.x += (float)yr[i1 + 0] + (float)yr[i2 + 0];
    o.y += (float)yr[i1 + 1] + (float)yr[i2 + 1];
    o.z += (float)yr[i1 + 2] + (float)yr[i2 + 2];
    o.w += (float)yr[i1 + 3] + (float)yr[i2 + 3];
    *(float4*)op = o;
}

extern "C" void kernel_launch(void* const* d_in, const int* in_sizes, int n_in,
                              void* d_out, int out_size, void* d_ws, size_t ws_size,
                              hipStream_t stream) {
    (void)in_sizes; (void)n_in; (void)out_size; (void)ws_size;
    const float* x   = (const float*)d_in[0];
    const float* wr  = (const float*)d_in[1];
    const float* w1  = (const float*)d_in[2];
    const float* w3  = (const float*)d_in[3];
    const float* w2  = (const float*)d_in[4];
    const float* sw1 = (const float*)d_in[5];
    const float* sw3 = (const float*)d_in[6];
    const float* sw2 = (const float*)d_in[7];
    float* outp = (float*)d_out;

    const size_t TD = (size_t)T_TOK * DMODEL;
    const size_t DH = (size_t)DMODEL * HIDDEN;
    auto al = [](size_t b) { return (b + 255) & ~(size_t)255; };

    char* p = (char*)d_ws;
    size_t off = 0;
    auto alloc = [&](size_t b) { char* r = p + off; off += al(b); return r; };

    int* cnt    = (int*)alloc(NEXP * 4);
    int* tok    = (int*)alloc((size_t)NEXP * T_TOK * 4);
    float* gate = (float*)alloc((size_t)NEXP * T_TOK * 4);
    int4* pairp = (int4*)alloc((size_t)T_TOK * 16);
    bf16_t* xb  = (bf16_t*)alloc(TD * 2);                      // 8.39 MB
    bf16_t* xg  = (bf16_t*)alloc((size_t)RTOT * DMODEL * 2);   // 16.78 MB

    const size_t wb_b = 9 * DH * 2;                            // 37.75 MB each
    char* wb1r  = alloc(wb_b);
    bf16_t* wb1 = (bf16_t*)wb1r;   // dead after gemm1
    bf16_t* yrp = (bf16_t*)wb1r;   // live gemm2..combine (16.78 MB, aliases wb1)
    bf16_t* wb3 = (bf16_t*)alloc(wb_b);
    bf16_t* wb2 = (bf16_t*)alloc(wb_b);
    bf16_t* act = (bf16_t*)alloc(((size_t)RTOT + T_TOK) * HIDDEN * 2);  // 50.33 MB
    // total ~189 MB

    hipMemsetAsync(cnt, 0, NEXP * 4, stream);
    router_kernel<<<dim3(T_TOK / 4), 256, 0, stream>>>(x, wr, cnt, tok, gate, pairp, xb);
    gather_kernel<<<dim3(NEXP * T_TOK / 2), 256, 0, stream>>>(xb, cnt, tok, xg);
    transpose_cvt_kernel<<<dim3(HIDDEN / 64, DMODEL / 64, 9), 256, 0, stream>>>(w1, sw1, wb1, DMODEL, HIDDEN);
    transpose_cvt_kernel<<<dim3(HIDDEN / 64, DMODEL / 64, 9), 256, 0, stream>>>(w3, sw3, wb3, DMODEL, HIDDEN);
    transpose_cvt_kernel<<<dim3(DMODEL / 64, HIDDEN / 64, 9), 256, 0, stream>>>(w2, sw2, wb2, HIDDEN, DMODEL);
    gemm1_kernel<<<dim3(HIDDEN / 64, T_TOK / 128, 9), 256, 0, stream>>>(xg, xb, wb1, wb3, cnt, act);
    gemm2_kernel<<<dim3(DMODEL / 128, T_TOK / 128, 9), 256, 0, stream>>>(act, wb2, cnt, gate, yrp, outp);
    combine_kernel<<<dim3(T_TOK), 256, 0, stream>>>(pairp, cnt, yrp, outp);
}